// Round 11
// baseline (136.883 us; speedup 1.0000x reference)
//
#include <hip/hip_runtime.h>

#define CC 8
#define HH 256
#define WW 512
#define KK 9
#define HWU (HH * WW)   // 131072 floats per channel image
#define XF 272          // x window row: 264 used, padded

// Dedup build: R0-R9 all issued the filter stream 4x (once per wave) ->
// ~380 MB of VMEM requests through the per-CU L1 path, constant across all
// ten variants (the one axis never varied; explains every null and every
// regression ratio). This kernel splits filter staging across waves via
// global_load_lds into block-shared LDS: wave w stages taps {w, w+4}, wave 3
// also tap 8. Publish protocol: each producer's own end-of-iter vmcnt(4)
// (only the 4 x-ops are newer) proves its taps landed; the raw s_barrier
// then publishes to consumers. Correctness is independent of per-wave op
// counts, so all waits are uniform vmcnt(4). x staging stays wave-private
// (already deduplicated). Steady state never drains vmcnt to 0.
__device__ __forceinline__ void gll16(const float* g, float* l) {
    __builtin_amdgcn_global_load_lds(
        (const __attribute__((address_space(1))) float*)g,
        (__attribute__((address_space(3))) float*)l,
        16, 0, 0);
}

__global__ __launch_bounds__(256, 4) void dynfilter_kernel(
    const float* __restrict__ x,
    const float* __restrict__ filt,
    const float* __restrict__ fbias,
    float* __restrict__ out)
{
    __shared__ __align__(16) float flds[2][KK][256];   // 18432 B, block-shared taps
    __shared__ __align__(16) float xs[4][2][2][XF];    // 17408 B, wave-private x rows

    const int tid  = threadIdx.x;
    const int wv   = tid >> 6;          // wave -> channels {2wv, 2wv+1}
    const int lane = tid & 63;

    // XCD-aware bijective swizzle (nwg=1024 % 8 == 0)
    const int bid0 = blockIdx.x;
    const int bid  = ((bid0 & 7) << 7) | (bid0 >> 3);

    const int seg = bid & 1;
    const int h   = (bid >> 1) & 255;
    const int n   = bid >> 9;

    const int w0      = seg * 256 + (lane << 2);   // 4 px per lane
    const int wstage0 = seg * 256 - 4;

    const int c0 = wv << 1;

    const float* fblk = filt + (size_t)(n * 81 * HH + h) * WW + seg * 256;
    const float* x0   = x + (size_t)(n * CC + c0) * HWU;
    const float* x1   = x0 + HWU;

    // full-exec per-lane x sources, clamped into [0, WW-4]:
    //   load A covers window[0..255], load B covers window[8..263];
    // overlap double-written with identical bytes (benign). Clamps fire only
    // at seg0/loadA/lane0 and seg1/loadB/lane63 -> exactly the fix_x cells.
    int wA = wstage0 + (lane << 2);
    int wB = wstage0 + 8 + (lane << 2);
    wA = wA < 0 ? 0 : (wA > WW - 4 ? WW - 4 : wA);
    wB = wB < 0 ? 0 : (wB > WW - 4 ? WW - 4 : wB);

    float acc0[4] = {0.f, 0.f, 0.f, 0.f};
    float acc1[4] = {0.f, 0.f, 0.f, 0.f};

    // one x row into wave-private buffer xb: exactly 4 vmcnt ops
    auto stage_x = [&](int r, int xb) {
        int hh = h - 4 + r;
        hh = hh < 0 ? 0 : (hh > HH - 1 ? HH - 1 : hh);
        const size_t ro = (size_t)hh * WW;
        float* d0 = &xs[wv][xb][0][0];
        float* d1 = &xs[wv][xb][1][0];
        gll16(x0 + ro + wA, d0);
        gll16(x0 + ro + wB, d0 + 8);
        gll16(x1 + ro + wA, d1);
        gll16(x1 + ro + wB, d1 + 8);
    };

    // DEDUPLICATED filter staging: this wave's share of tap-row (2 or 3 ops).
    // Union over waves = taps {0..8}, no overlap.
    auto stage_f = [&](const float* frow, int fb) {
        float* d = &flds[fb][0][0];
        gll16(frow + (size_t)wv * HWU + (lane << 2), d + wv * 256);
        gll16(frow + (size_t)(wv + 4) * HWU + (lane << 2), d + (wv + 4) * 256);
        if (wv == 3)
            gll16(frow + (size_t)8 * HWU + (lane << 2), d + 8 * 256);
    };

    // post-wait cleanup of buffer xb holding row (h-4+r): whole-row zero if
    // outside the image, else zero the 4 halo floats (seg0: window[0..3];
    // seg1: window[260..263]). lane<2 trick: lane==ch index.
    auto fix_x = [&](int xb, int r) {
        const float4 z = make_float4(0.f, 0.f, 0.f, 0.f);
        const int hh = h - 4 + r;
        if ((unsigned)hh >= (unsigned)HH) {
            *(float4*)&xs[wv][xb][0][lane << 2] = z;
            *(float4*)&xs[wv][xb][1][lane << 2] = z;
            if (lane < 2) {
                *(float4*)&xs[wv][xb][0][256 + (lane << 2)] = z;
                *(float4*)&xs[wv][xb][1][256 + (lane << 2)] = z;
            }
        } else if (lane < 2) {
            *(float4*)&xs[wv][xb][lane][seg ? 260 : 0] = z;
        }
    };

    // drain compiler-issued VMEM so manual vmcnt counting is exact
    asm volatile("s_waitcnt vmcnt(0)" ::: "memory");

    // ---- prologue ----
    stage_f(fblk, 0);     // own share of f(0)
    stage_x(0, 0);        // 4 ops
    stage_x(1, 1);        // 4 ops
    // newest 4 in flight = x(1) -> own f(0) and x(0) landed
    asm volatile("s_waitcnt vmcnt(4)" ::: "memory");
    __builtin_amdgcn_sched_barrier(0);
    __builtin_amdgcn_s_barrier();      // publish f(0)
    __builtin_amdgcn_sched_barrier(0);

    const float* frow = fblk + 9 * HWU;   // tap-row 1

    #pragma clang loop unroll(disable)
    for (int i = 0; i < KK - 1; ++i) {
        const int buf = i & 1;

        stage_f(frow, buf ^ 1);           // own share of f(i+1)
        frow += 9 * HWU;

        fix_x(buf, i);
        __builtin_amdgcn_sched_barrier(0);

        // reads: f(i) published by last barrier; x(i) landed by last vmcnt(4)
        float4 f[9];
        {
            const float* fp = &flds[buf][0][lane << 2];
            #pragma unroll
            for (int j = 0; j < 9; ++j) f[j] = *(const float4*)(fp + j * 256);
        }
        float v0[12], v1[12];
        {
            const float* p0 = &xs[wv][buf][0][lane << 2];
            const float* p1 = &xs[wv][buf][1][lane << 2];
            float4 u;
            u = *(const float4*)(p0 + 0); v0[0]=u.x; v0[1]=u.y; v0[2] =u.z; v0[3] =u.w;
            u = *(const float4*)(p0 + 4); v0[4]=u.x; v0[5]=u.y; v0[6] =u.z; v0[7] =u.w;
            u = *(const float4*)(p0 + 8); v0[8]=u.x; v0[9]=u.y; v0[10]=u.z; v0[11]=u.w;
            u = *(const float4*)(p1 + 0); v1[0]=u.x; v1[1]=u.y; v1[2] =u.z; v1[3] =u.w;
            u = *(const float4*)(p1 + 4); v1[4]=u.x; v1[5]=u.y; v1[6] =u.z; v1[7] =u.w;
            u = *(const float4*)(p1 + 8); v1[8]=u.x; v1[9]=u.y; v1[10]=u.z; v1[11]=u.w;
        }

        // 72 FMAs (2 ch x 4 px x 9 taps)
        #pragma unroll
        for (int j = 0; j < 9; ++j) {
            acc0[0] = fmaf(f[j].x, v0[j+0], acc0[0]);
            acc0[1] = fmaf(f[j].y, v0[j+1], acc0[1]);
            acc0[2] = fmaf(f[j].z, v0[j+2], acc0[2]);
            acc0[3] = fmaf(f[j].w, v0[j+3], acc0[3]);
            acc1[0] = fmaf(f[j].x, v1[j+0], acc1[0]);
            acc1[1] = fmaf(f[j].y, v1[j+1], acc1[1]);
            acc1[2] = fmaf(f[j].z, v1[j+2], acc1[2]);
            acc1[3] = fmaf(f[j].w, v1[j+3], acc1[3]);
        }

        // refill just-consumed x buffer (ds_reads above provably retired:
        // their data fed the FMAs)
        __builtin_amdgcn_sched_barrier(0);
        stage_x(i + 2, buf);              // x(i+2): 4 ops

        // newest 4 in flight = x(i+2) -> own f(i+1) share and x(i+1) landed;
        // barrier publishes f(i+1) and bounds wave drift to 0 iterations.
        asm volatile("s_waitcnt vmcnt(4)" ::: "memory");
        __builtin_amdgcn_sched_barrier(0);
        __builtin_amdgcn_s_barrier();
        __builtin_amdgcn_sched_barrier(0);
    }

    // ---- epilogue: f(8) in flds[0], x(8) in xs[0]; x(9) still in flight ----
    fix_x(0, 8);
    __builtin_amdgcn_sched_barrier(0);

    {
        float4 f[9];
        const float* fp = &flds[0][0][lane << 2];
        #pragma unroll
        for (int j = 0; j < 9; ++j) f[j] = *(const float4*)(fp + j * 256);

        float v0[12], v1[12];
        const float* p0 = &xs[wv][0][0][lane << 2];
        const float* p1 = &xs[wv][0][1][lane << 2];
        float4 u;
        u = *(const float4*)(p0 + 0); v0[0]=u.x; v0[1]=u.y; v0[2] =u.z; v0[3] =u.w;
        u = *(const float4*)(p0 + 4); v0[4]=u.x; v0[5]=u.y; v0[6] =u.z; v0[7] =u.w;
        u = *(const float4*)(p0 + 8); v0[8]=u.x; v0[9]=u.y; v0[10]=u.z; v0[11]=u.w;
        u = *(const float4*)(p1 + 0); v1[0]=u.x; v1[1]=u.y; v1[2] =u.z; v1[3] =u.w;
        u = *(const float4*)(p1 + 4); v1[4]=u.x; v1[5]=u.y; v1[6] =u.z; v1[7] =u.w;
        u = *(const float4*)(p1 + 8); v1[8]=u.x; v1[9]=u.y; v1[10]=u.z; v1[11]=u.w;

        #pragma unroll
        for (int j = 0; j < 9; ++j) {
            acc0[0] = fmaf(f[j].x, v0[j+0], acc0[0]);
            acc0[1] = fmaf(f[j].y, v0[j+1], acc0[1]);
            acc0[2] = fmaf(f[j].z, v0[j+2], acc0[2]);
            acc0[3] = fmaf(f[j].w, v0[j+3], acc0[3]);
            acc1[0] = fmaf(f[j].x, v1[j+0], acc1[0]);
            acc1[1] = fmaf(f[j].y, v1[j+1], acc1[1]);
            acc1[2] = fmaf(f[j].z, v1[j+2], acc1[2]);
            acc1[3] = fmaf(f[j].w, v1[j+3], acc1[3]);
        }
    }

    // bias (after all counted waits) + store
    {
        const float4 b4 = *(const float4*)(fbias + ((size_t)(n * HH + h)) * WW + w0);
        const float4 o0 = make_float4(acc0[0] + b4.x, acc0[1] + b4.y,
                                      acc0[2] + b4.z, acc0[3] + b4.w);
        const float4 o1 = make_float4(acc1[0] + b4.x, acc1[1] + b4.y,
                                      acc1[2] + b4.z, acc1[3] + b4.w);
        *(float4*)(out + ((size_t)(n * CC + c0)     * HH + h) * WW + w0) = o0;
        *(float4*)(out + ((size_t)(n * CC + c0 + 1) * HH + h) * WW + w0) = o1;
    }
}

extern "C" void kernel_launch(void* const* d_in, const int* in_sizes, int n_in,
                              void* d_out, int out_size, void* d_ws, size_t ws_size,
                              hipStream_t stream) {
    const float* x  = (const float*)d_in[0];
    const float* f  = (const float*)d_in[1];
    const float* fb = (const float*)d_in[2];
    float* o = (float*)d_out;
    hipLaunchKernelGGL(dynfilter_kernel, dim3(1024), dim3(256), 0, stream,
                       x, f, fb, o);
}